// Round 1
// baseline (754.158 us; speedup 1.0000x reference)
//
#include <hip/hip_runtime.h>
#include <stdint.h>

#define NDIM 64

// ---------------- CSR build ----------------

__global__ __launch_bounds__(256) void degree_kernel(
    const int* __restrict__ src, const int* __restrict__ dst,
    int* __restrict__ deg_d, int* __restrict__ deg_s, int E, int N) {
  int e = blockIdx.x * blockDim.x + threadIdx.x;
  if (e >= E) return;
  int s = src[e], d = dst[e];
  if ((unsigned)d < (unsigned)N) atomicAdd(&deg_d[d], 1);
  if ((unsigned)s < (unsigned)N) atomicAdd(&deg_s[s], 1);
}

__global__ __launch_bounds__(1024) void scan_kernel(
    const int* __restrict__ deg, int* __restrict__ row, int n) {
  __shared__ int part[1024];
  int tid = threadIdx.x;
  int per = (n + 1023) >> 10;
  int base = tid * per;
  int s = 0;
  for (int j = 0; j < per; ++j) {
    int i = base + j;
    if (i < n) s += deg[i];
  }
  part[tid] = s;
  __syncthreads();
  for (int off = 1; off < 1024; off <<= 1) {
    int v = (tid >= off) ? part[tid - off] : 0;
    __syncthreads();
    part[tid] += v;
    __syncthreads();
  }
  int run = (tid == 0) ? 0 : part[tid - 1];
  for (int j = 0; j < per; ++j) {
    int i = base + j;
    if (i < n) { row[i] = run; run += deg[i]; }
  }
  if (tid == 1023) row[n] = run;
}

__global__ __launch_bounds__(256) void fill_kernel(
    const int* __restrict__ src, const int* __restrict__ dst,
    const int* __restrict__ row_d, int* __restrict__ cur_d, int* __restrict__ col_d,
    const int* __restrict__ row_s, int* __restrict__ cur_s, int* __restrict__ col_s,
    int E, int N) {
  int e = blockIdx.x * blockDim.x + threadIdx.x;
  if (e >= E) return;
  int s = src[e], d = dst[e];
  if ((unsigned)d < (unsigned)N && (unsigned)s < (unsigned)N) {
    int p = atomicAdd(&cur_d[d], 1);
    col_d[row_d[d] + p] = s;
    int q = atomicAdd(&cur_s[s], 1);
    col_s[row_s[s] + q] = d;
  }
}

// ---------------- aggregation: wave per node, lane = feature ----------------

__global__ __launch_bounds__(256) void agg_kernel(
    const float* __restrict__ h, const int* __restrict__ row,
    const int* __restrict__ col, float* __restrict__ outp, int N) {
  int wid = blockIdx.x * 4 + (threadIdx.x >> 6);
  int lane = threadIdx.x & 63;
  if (wid >= N) return;
  int s0 = row[wid], s1 = row[wid + 1];
  float a0 = 0.f, a1 = 0.f, a2 = 0.f, a3 = 0.f;
  int p = s0;
  for (; p + 4 <= s1; p += 4) {
    int n0 = col[p], n1 = col[p + 1], n2 = col[p + 2], n3 = col[p + 3];
    a0 += h[(size_t)n0 * NDIM + lane];
    a1 += h[(size_t)n1 * NDIM + lane];
    a2 += h[(size_t)n2 * NDIM + lane];
    a3 += h[(size_t)n3 * NDIM + lane];
  }
  for (; p < s1; ++p) a0 += h[(size_t)col[p] * NDIM + lane];
  float sum = (a0 + a1) + (a2 + a3);
  int cnt = s1 - s0;
  float inv = cnt > 0 ? 1.f / (float)cnt : 0.f;
  outp[(size_t)wid * NDIM + lane] = sum * inv;
}

// ---------------- combine: h_out = relu(h@R^T + b + g1@W1^T + g2@W2^T) ----------------

#define STEP3(V0, V1, V2, KROW) {                                            \
    const float4* wr4_ = (const float4*)&Wr[(KROW) * 64];                    \
    const float4* w14_ = (const float4*)&W1[(KROW) * 64];                    \
    const float4* w24_ = (const float4*)&W2[(KROW) * 64];                    \
    _Pragma("unroll")                                                        \
    for (int o4_ = 0; o4_ < 16; ++o4_) {                                     \
      float4 wa_ = wr4_[o4_], wb_ = w14_[o4_], wc_ = w24_[o4_];              \
      acc[4 * o4_ + 0] += (V0) * wa_.x + (V1) * wb_.x + (V2) * wc_.x;        \
      acc[4 * o4_ + 1] += (V0) * wa_.y + (V1) * wb_.y + (V2) * wc_.y;        \
      acc[4 * o4_ + 2] += (V0) * wa_.z + (V1) * wb_.z + (V2) * wc_.z;        \
      acc[4 * o4_ + 3] += (V0) * wa_.w + (V1) * wb_.w + (V2) * wc_.w;        \
    } }

__global__ __launch_bounds__(256) void combine_kernel(
    const float* __restrict__ h, const float* __restrict__ g1,
    const float* __restrict__ g2, const float* __restrict__ wr,
    const float* __restrict__ w1, const float* __restrict__ w2,
    const float* __restrict__ bias, float* __restrict__ hout, int N) {
  __shared__ float Wr[64 * 64];
  __shared__ float W1[64 * 64];
  __shared__ float W2[64 * 64];
  __shared__ float B[64];
  int tid = threadIdx.x;
  for (int i = 0; i < 4; ++i) {
    int f4 = i * 256 + tid;
    int o = f4 >> 4;
    int kb = (f4 & 15) << 2;
    float4 vr = ((const float4*)wr)[f4];
    float4 v1 = ((const float4*)w1)[f4];
    float4 v2 = ((const float4*)w2)[f4];
    Wr[(kb + 0) * 64 + o] = vr.x; Wr[(kb + 1) * 64 + o] = vr.y;
    Wr[(kb + 2) * 64 + o] = vr.z; Wr[(kb + 3) * 64 + o] = vr.w;
    W1[(kb + 0) * 64 + o] = v1.x; W1[(kb + 1) * 64 + o] = v1.y;
    W1[(kb + 2) * 64 + o] = v1.z; W1[(kb + 3) * 64 + o] = v1.w;
    W2[(kb + 0) * 64 + o] = v2.x; W2[(kb + 1) * 64 + o] = v2.y;
    W2[(kb + 2) * 64 + o] = v2.z; W2[(kb + 3) * 64 + o] = v2.w;
  }
  if (tid < 64) B[tid] = bias[tid];
  __syncthreads();
  int node = blockIdx.x * 256 + tid;
  if (node >= N) return;
  float acc[64];
#pragma unroll
  for (int o = 0; o < 64; ++o) acc[o] = B[o];
  const float4* hp = (const float4*)(h + (size_t)node * NDIM);
  const float4* p1 = (const float4*)(g1 + (size_t)node * NDIM);
  const float4* p2 = (const float4*)(g2 + (size_t)node * NDIM);
  float4 hc = hp[0], c1 = p1[0], c2 = p2[0];
  for (int k4 = 0; k4 < 16; ++k4) {
    float4 hn = hc, n1 = c1, n2 = c2;
    if (k4 < 15) { hn = hp[k4 + 1]; n1 = p1[k4 + 1]; n2 = p2[k4 + 1]; }
    int kb = k4 * 4;
    STEP3(hc.x, c1.x, c2.x, kb + 0);
    STEP3(hc.y, c1.y, c2.y, kb + 1);
    STEP3(hc.z, c1.z, c2.z, kb + 2);
    STEP3(hc.w, c1.w, c2.w, kb + 3);
    hc = hn; c1 = n1; c2 = n2;
  }
  float4* op = (float4*)(hout + (size_t)node * NDIM);
#pragma unroll
  for (int o4 = 0; o4 < 16; ++o4) {
    float4 v;
    v.x = fmaxf(acc[4 * o4 + 0], 0.f);
    v.y = fmaxf(acc[4 * o4 + 1], 0.f);
    v.z = fmaxf(acc[4 * o4 + 2], 0.f);
    v.w = fmaxf(acc[4 * o4 + 3], 0.f);
    op[o4] = v;
  }
}

// ---------------- final: out = [x,h1,h2,h3] @ final_w^T + final_b ----------------

#define FSTEP(V, KROW) {                                                     \
    const float4* w4_ = (const float4*)&Wt[(KROW) * 64];                     \
    _Pragma("unroll")                                                        \
    for (int o4_ = 0; o4_ < 16; ++o4_) {                                     \
      float4 w_ = w4_[o4_];                                                  \
      acc[4 * o4_ + 0] += (V) * w_.x;                                        \
      acc[4 * o4_ + 1] += (V) * w_.y;                                        \
      acc[4 * o4_ + 2] += (V) * w_.z;                                        \
      acc[4 * o4_ + 3] += (V) * w_.w;                                        \
    } }

#define FBLOCK(PTR, ABASE) {                                                 \
    const float4* ip_ = (const float4*)((PTR) + (size_t)node * NDIM);        \
    float4 c_ = ip_[0];                                                      \
    for (int k4_ = 0; k4_ < 16; ++k4_) {                                     \
      float4 n_ = c_;                                                        \
      if (k4_ < 15) n_ = ip_[k4_ + 1];                                       \
      int kr_ = (ABASE) + k4_ * 4;                                           \
      FSTEP(c_.x, kr_ + 0);                                                  \
      FSTEP(c_.y, kr_ + 1);                                                  \
      FSTEP(c_.z, kr_ + 2);                                                  \
      FSTEP(c_.w, kr_ + 3);                                                  \
      c_ = n_;                                                               \
    } }

__global__ __launch_bounds__(256) void final_kernel(
    const float* __restrict__ x, const float* __restrict__ h1,
    const float* __restrict__ h2, const float* __restrict__ h3,
    const float* __restrict__ fw, const float* __restrict__ fb,
    float* __restrict__ outp, int N) {
  __shared__ float Wt[256 * 64];
  int tid = threadIdx.x;
  for (int i = 0; i < 16; ++i) {
    int f4 = i * 256 + tid;
    int o = f4 >> 6;
    int kc = f4 & 63;
    float4 v = ((const float4*)fw)[f4];
    int kb = kc * 4;
    Wt[(kb + 0) * 64 + o] = v.x; Wt[(kb + 1) * 64 + o] = v.y;
    Wt[(kb + 2) * 64 + o] = v.z; Wt[(kb + 3) * 64 + o] = v.w;
  }
  __syncthreads();
  int node = blockIdx.x * 256 + tid;
  if (node >= N) return;
  float acc[64];
#pragma unroll
  for (int o = 0; o < 64; ++o) acc[o] = fb[o];
  FBLOCK(x, 0)
  FBLOCK(h1, 64)
  FBLOCK(h2, 128)
  FBLOCK(h3, 192)
  float4* op = (float4*)(outp + (size_t)node * NDIM);
#pragma unroll
  for (int o4 = 0; o4 < 16; ++o4) {
    float4 v;
    v.x = acc[4 * o4 + 0]; v.y = acc[4 * o4 + 1];
    v.z = acc[4 * o4 + 2]; v.w = acc[4 * o4 + 3];
    op[o4] = v;
  }
}

// ---------------- launch ----------------

extern "C" void kernel_launch(void* const* d_in, const int* in_sizes, int n_in,
                              void* d_out, int out_size, void* d_ws, size_t ws_size,
                              hipStream_t stream) {
  const float* x     = (const float*)d_in[0];
  const int*   ei    = (const int*)d_in[1];
  const float* lin1  = (const float*)d_in[2];
  const float* lin2  = (const float*)d_in[3];
  const float* rootw = (const float*)d_in[4];
  const float* rootb = (const float*)d_in[5];
  const float* fw    = (const float*)d_in[6];
  const float* fb    = (const float*)d_in[7];
  float* out = (float*)d_out;

  int N = in_sizes[0] / NDIM;
  int E = in_sizes[1] / 2;
  const int* src = ei;
  const int* dst = ei + E;

  int* ip = (int*)d_ws;
  int* deg_d = ip; ip += N;
  int* deg_s = ip; ip += N;
  int* cur_d = ip; ip += N;
  int* cur_s = ip; ip += N;
  int* row_d = ip; ip += N + 1;
  int* row_s = ip; ip += N + 1;
  int* col_d = ip; ip += E;
  int* col_s = ip; ip += E;
  uintptr_t fbase = (((uintptr_t)ip) + 255) & ~(uintptr_t)255;
  float* h1 = (float*)fbase;
  float* h2 = h1 + (size_t)N * NDIM;
  float* h3 = h2 + (size_t)N * NDIM;
  float* g1 = h3 + (size_t)N * NDIM;
  float* g2 = g1 + (size_t)N * NDIM;

  hipMemsetAsync(deg_d, 0, sizeof(int) * (size_t)4 * N, stream);

  int eb = (E + 255) / 256;
  degree_kernel<<<eb, 256, 0, stream>>>(src, dst, deg_d, deg_s, E, N);
  scan_kernel<<<1, 1024, 0, stream>>>(deg_d, row_d, N);
  scan_kernel<<<1, 1024, 0, stream>>>(deg_s, row_s, N);
  fill_kernel<<<eb, 256, 0, stream>>>(src, dst, row_d, cur_d, col_d,
                                      row_s, cur_s, col_s, E, N);

  int ab = (N + 3) / 4;
  int nb = (N + 255) / 256;
  const float* hbufs[4] = {x, h1, h2, h3};
  for (int l = 0; l < 3; ++l) {
    const float* hin = hbufs[l];
    float* hout = (float*)hbufs[l + 1];
    agg_kernel<<<ab, 256, 0, stream>>>(hin, row_d, col_d, g1, N);
    agg_kernel<<<ab, 256, 0, stream>>>(hin, row_s, col_s, g2, N);
    combine_kernel<<<nb, 256, 0, stream>>>(hin, g1, g2,
                                           rootw + (size_t)l * 4096,
                                           lin1 + (size_t)l * 4096,
                                           lin2 + (size_t)l * 4096,
                                           rootb + (size_t)l * 64, hout, N);
  }
  final_kernel<<<nb, 256, 0, stream>>>(x, h1, h2, h3, fw, fb, out, N);
}

// Round 2
// 552.795 us; speedup vs baseline: 1.3643x; 1.3643x over previous
//
#include <hip/hip_runtime.h>
#include <stdint.h>

#define NDIM 64
#define SCAN_ELEMS 2048   // elements per scan block (256 thr x 8)

// ---------------- CSR build ----------------

__global__ __launch_bounds__(256) void degree_kernel(
    const int* __restrict__ src, const int* __restrict__ dst,
    int* __restrict__ deg_d, int* __restrict__ deg_s, int E, int N) {
  int e = blockIdx.x * blockDim.x + threadIdx.x;
  if (e >= E) return;
  int s = src[e], d = dst[e];
  if ((unsigned)d < (unsigned)N) atomicAdd(&deg_d[d], 1);
  if ((unsigned)s < (unsigned)N) atomicAdd(&deg_s[s], 1);
}

// phase 1: per-block sums of deg_d (y=0) / deg_s (y=1)
__global__ __launch_bounds__(256) void scan_partial(
    const int* __restrict__ deg_d, const int* __restrict__ deg_s,
    int* __restrict__ bsum, int n, int nb) {
  const int* deg = (blockIdx.y == 0) ? deg_d : deg_s;
  int tid = threadIdx.x;
  int base = blockIdx.x * SCAN_ELEMS;
  int s = 0;
#pragma unroll
  for (int j = 0; j < 8; ++j) {
    int i = base + j * 256 + tid;
    if (i < n) s += deg[i];
  }
#pragma unroll
  for (int off = 1; off < 64; off <<= 1) s += __shfl_xor(s, off);
  __shared__ int ws[4];
  if ((tid & 63) == 0) ws[tid >> 6] = s;
  __syncthreads();
  if (tid == 0) bsum[blockIdx.y * nb + blockIdx.x] = ws[0] + ws[1] + ws[2] + ws[3];
}

// phase 2: exclusive-scan the block sums (nb <= 256), both halves
__global__ __launch_bounds__(256) void scan_bsum(int* __restrict__ bsum, int nb) {
  __shared__ int sh[256];
  int tid = threadIdx.x;
  for (int h = 0; h < 2; ++h) {
    int v = (tid < nb) ? bsum[h * nb + tid] : 0;
    sh[tid] = v;
    __syncthreads();
    for (int off = 1; off < 256; off <<= 1) {
      int t = (tid >= off) ? sh[tid - off] : 0;
      __syncthreads();
      sh[tid] += t;
      __syncthreads();
    }
    if (tid < nb) bsum[h * nb + tid] = sh[tid] - v;  // exclusive
    __syncthreads();
  }
}

// phase 3: per-block exclusive scan + block offset; writes row[0..n]
__global__ __launch_bounds__(256) void scan_final(
    const int* __restrict__ deg_d, const int* __restrict__ deg_s,
    const int* __restrict__ bsum,
    int* __restrict__ row_d, int* __restrict__ row_s, int n, int nb) {
  const int* deg = (blockIdx.y == 0) ? deg_d : deg_s;
  int* row = (blockIdx.y == 0) ? row_d : row_s;
  int tid = threadIdx.x;
  int lane = tid & 63;
  int e0 = blockIdx.x * SCAN_ELEMS + tid * 8;
  int v[8];
  int s = 0;
#pragma unroll
  for (int j = 0; j < 8; ++j) {
    int i = e0 + j;
    v[j] = (i < n) ? deg[i] : 0;
    s += v[j];
  }
  // wave-inclusive scan of per-thread sums
  int incl = s;
#pragma unroll
  for (int off = 1; off < 64; off <<= 1) {
    int t = __shfl_up(incl, off);
    if (lane >= off) incl += t;
  }
  __shared__ int wsum[4];
  if (lane == 63) wsum[tid >> 6] = incl;
  __syncthreads();
  int woff = 0;
  int w = tid >> 6;
  for (int k = 0; k < 4; ++k)
    if (k < w) woff += wsum[k];
  int run = incl - s + woff + bsum[blockIdx.y * nb + blockIdx.x];
#pragma unroll
  for (int j = 0; j < 8; ++j) {
    int i = e0 + j;
    if (i <= n) row[i] = run;
    run += v[j];
  }
}

__global__ __launch_bounds__(256) void fill_kernel(
    const int* __restrict__ src, const int* __restrict__ dst,
    const int* __restrict__ row_d, int* __restrict__ cur_d, int* __restrict__ col_d,
    const int* __restrict__ row_s, int* __restrict__ cur_s, int* __restrict__ col_s,
    int E, int N) {
  int e = blockIdx.x * blockDim.x + threadIdx.x;
  if (e >= E) return;
  int s = src[e], d = dst[e];
  if ((unsigned)d < (unsigned)N && (unsigned)s < (unsigned)N) {
    int p = atomicAdd(&cur_d[d], 1);
    col_d[row_d[d] + p] = s;
    int q = atomicAdd(&cur_s[s], 1);
    col_s[row_s[s] + q] = d;
  }
}

// ---------------- aggregation: wave per node, lane = feature; y selects direction ----------------

__global__ __launch_bounds__(256) void agg2_kernel(
    const float* __restrict__ h,
    const int* __restrict__ row_d, const int* __restrict__ col_d, float* __restrict__ g1,
    const int* __restrict__ row_s, const int* __restrict__ col_s, float* __restrict__ g2,
    int N) {
  const int* row = (blockIdx.y == 0) ? row_d : row_s;
  const int* col = (blockIdx.y == 0) ? col_d : col_s;
  float* outp = (blockIdx.y == 0) ? g1 : g2;
  int wid = blockIdx.x * 4 + (threadIdx.x >> 6);
  int lane = threadIdx.x & 63;
  if (wid >= N) return;
  int s0 = row[wid], s1 = row[wid + 1];
  float a0 = 0.f, a1 = 0.f, a2 = 0.f, a3 = 0.f;
  int p = s0;
  for (; p + 4 <= s1; p += 4) {
    int n0 = col[p], n1 = col[p + 1], n2 = col[p + 2], n3 = col[p + 3];
    a0 += h[(size_t)n0 * NDIM + lane];
    a1 += h[(size_t)n1 * NDIM + lane];
    a2 += h[(size_t)n2 * NDIM + lane];
    a3 += h[(size_t)n3 * NDIM + lane];
  }
  for (; p < s1; ++p) a0 += h[(size_t)col[p] * NDIM + lane];
  float sum = (a0 + a1) + (a2 + a3);
  int cnt = s1 - s0;
  float inv = cnt > 0 ? 1.f / (float)cnt : 0.f;
  outp[(size_t)wid * NDIM + lane] = sum * inv;
}

// ---------------- combine: h_out = relu(h@R^T + b + g1@W1^T + g2@W2^T) ----------------

#define STEP3(V0, V1, V2, KROW) {                                            \
    const float4* wr4_ = (const float4*)&Wr[(KROW) * 64];                    \
    const float4* w14_ = (const float4*)&W1[(KROW) * 64];                    \
    const float4* w24_ = (const float4*)&W2[(KROW) * 64];                    \
    _Pragma("unroll")                                                        \
    for (int o4_ = 0; o4_ < 16; ++o4_) {                                     \
      float4 wa_ = wr4_[o4_], wb_ = w14_[o4_], wc_ = w24_[o4_];              \
      acc[4 * o4_ + 0] += (V0) * wa_.x + (V1) * wb_.x + (V2) * wc_.x;        \
      acc[4 * o4_ + 1] += (V0) * wa_.y + (V1) * wb_.y + (V2) * wc_.y;        \
      acc[4 * o4_ + 2] += (V0) * wa_.z + (V1) * wb_.z + (V2) * wc_.z;        \
      acc[4 * o4_ + 3] += (V0) * wa_.w + (V1) * wb_.w + (V2) * wc_.w;        \
    } }

__global__ __launch_bounds__(256) void combine_kernel(
    const float* __restrict__ h, const float* __restrict__ g1,
    const float* __restrict__ g2, const float* __restrict__ wr,
    const float* __restrict__ w1, const float* __restrict__ w2,
    const float* __restrict__ bias, float* __restrict__ hout, int N) {
  __shared__ float Wr[64 * 64];
  __shared__ float W1[64 * 64];
  __shared__ float W2[64 * 64];
  __shared__ float B[64];
  int tid = threadIdx.x;
  for (int i = 0; i < 4; ++i) {
    int f4 = i * 256 + tid;
    int o = f4 >> 4;
    int kb = (f4 & 15) << 2;
    float4 vr = ((const float4*)wr)[f4];
    float4 v1 = ((const float4*)w1)[f4];
    float4 v2 = ((const float4*)w2)[f4];
    Wr[(kb + 0) * 64 + o] = vr.x; Wr[(kb + 1) * 64 + o] = vr.y;
    Wr[(kb + 2) * 64 + o] = vr.z; Wr[(kb + 3) * 64 + o] = vr.w;
    W1[(kb + 0) * 64 + o] = v1.x; W1[(kb + 1) * 64 + o] = v1.y;
    W1[(kb + 2) * 64 + o] = v1.z; W1[(kb + 3) * 64 + o] = v1.w;
    W2[(kb + 0) * 64 + o] = v2.x; W2[(kb + 1) * 64 + o] = v2.y;
    W2[(kb + 2) * 64 + o] = v2.z; W2[(kb + 3) * 64 + o] = v2.w;
  }
  if (tid < 64) B[tid] = bias[tid];
  __syncthreads();
  int node = blockIdx.x * 256 + tid;
  if (node >= N) return;
  float acc[64];
#pragma unroll
  for (int o = 0; o < 64; ++o) acc[o] = B[o];
  const float4* hp = (const float4*)(h + (size_t)node * NDIM);
  const float4* p1 = (const float4*)(g1 + (size_t)node * NDIM);
  const float4* p2 = (const float4*)(g2 + (size_t)node * NDIM);
  float4 hc = hp[0], c1 = p1[0], c2 = p2[0];
  for (int k4 = 0; k4 < 16; ++k4) {
    float4 hn = hc, n1 = c1, n2 = c2;
    if (k4 < 15) { hn = hp[k4 + 1]; n1 = p1[k4 + 1]; n2 = p2[k4 + 1]; }
    int kb = k4 * 4;
    STEP3(hc.x, c1.x, c2.x, kb + 0);
    STEP3(hc.y, c1.y, c2.y, kb + 1);
    STEP3(hc.z, c1.z, c2.z, kb + 2);
    STEP3(hc.w, c1.w, c2.w, kb + 3);
    hc = hn; c1 = n1; c2 = n2;
  }
  float4* op = (float4*)(hout + (size_t)node * NDIM);
#pragma unroll
  for (int o4 = 0; o4 < 16; ++o4) {
    float4 v;
    v.x = fmaxf(acc[4 * o4 + 0], 0.f);
    v.y = fmaxf(acc[4 * o4 + 1], 0.f);
    v.z = fmaxf(acc[4 * o4 + 2], 0.f);
    v.w = fmaxf(acc[4 * o4 + 3], 0.f);
    op[o4] = v;
  }
}

// ---------------- final: out = [x,h1,h2,h3] @ final_w^T + final_b ----------------

#define FSTEP(V, KROW) {                                                     \
    const float4* w4_ = (const float4*)&Wt[(KROW) * 64];                     \
    _Pragma("unroll")                                                        \
    for (int o4_ = 0; o4_ < 16; ++o4_) {                                     \
      float4 w_ = w4_[o4_];                                                  \
      acc[4 * o4_ + 0] += (V) * w_.x;                                        \
      acc[4 * o4_ + 1] += (V) * w_.y;                                        \
      acc[4 * o4_ + 2] += (V) * w_.z;                                        \
      acc[4 * o4_ + 3] += (V) * w_.w;                                        \
    } }

#define FBLOCK(PTR, ABASE) {                                                 \
    const float4* ip_ = (const float4*)((PTR) + (size_t)node * NDIM);        \
    float4 c_ = ip_[0];                                                      \
    for (int k4_ = 0; k4_ < 16; ++k4_) {                                     \
      float4 n_ = c_;                                                        \
      if (k4_ < 15) n_ = ip_[k4_ + 1];                                       \
      int kr_ = (ABASE) + k4_ * 4;                                           \
      FSTEP(c_.x, kr_ + 0);                                                  \
      FSTEP(c_.y, kr_ + 1);                                                  \
      FSTEP(c_.z, kr_ + 2);                                                  \
      FSTEP(c_.w, kr_ + 3);                                                  \
      c_ = n_;                                                               \
    } }

__global__ __launch_bounds__(256) void final_kernel(
    const float* __restrict__ x, const float* __restrict__ h1,
    const float* __restrict__ h2, const float* __restrict__ h3,
    const float* __restrict__ fw, const float* __restrict__ fb,
    float* __restrict__ outp, int N) {
  __shared__ float Wt[256 * 64];
  int tid = threadIdx.x;
  for (int i = 0; i < 16; ++i) {
    int f4 = i * 256 + tid;
    int o = f4 >> 6;
    int kc = f4 & 63;
    float4 v = ((const float4*)fw)[f4];
    int kb = kc * 4;
    Wt[(kb + 0) * 64 + o] = v.x; Wt[(kb + 1) * 64 + o] = v.y;
    Wt[(kb + 2) * 64 + o] = v.z; Wt[(kb + 3) * 64 + o] = v.w;
  }
  __syncthreads();
  int node = blockIdx.x * 256 + tid;
  if (node >= N) return;
  float acc[64];
#pragma unroll
  for (int o = 0; o < 64; ++o) acc[o] = fb[o];
  FBLOCK(x, 0)
  FBLOCK(h1, 64)
  FBLOCK(h2, 128)
  FBLOCK(h3, 192)
  float4* op = (float4*)(outp + (size_t)node * NDIM);
#pragma unroll
  for (int o4 = 0; o4 < 16; ++o4) {
    float4 v;
    v.x = acc[4 * o4 + 0]; v.y = acc[4 * o4 + 1];
    v.z = acc[4 * o4 + 2]; v.w = acc[4 * o4 + 3];
    op[o4] = v;
  }
}

// ---------------- launch ----------------

extern "C" void kernel_launch(void* const* d_in, const int* in_sizes, int n_in,
                              void* d_out, int out_size, void* d_ws, size_t ws_size,
                              hipStream_t stream) {
  const float* x     = (const float*)d_in[0];
  const int*   ei    = (const int*)d_in[1];
  const float* lin1  = (const float*)d_in[2];
  const float* lin2  = (const float*)d_in[3];
  const float* rootw = (const float*)d_in[4];
  const float* rootb = (const float*)d_in[5];
  const float* fw    = (const float*)d_in[6];
  const float* fb    = (const float*)d_in[7];
  float* out = (float*)d_out;

  int N = in_sizes[0] / NDIM;
  int E = in_sizes[1] / 2;
  const int* src = ei;
  const int* dst = ei + E;

  int* ip = (int*)d_ws;
  int* deg_d = ip; ip += N;
  int* deg_s = ip; ip += N;
  int* cur_d = ip; ip += N;
  int* cur_s = ip; ip += N;
  int* row_d = ip; ip += N + 1;
  int* row_s = ip; ip += N + 1;
  int* bsum  = ip; ip += 256;
  int* col_d = ip; ip += E;
  int* col_s = ip; ip += E;
  uintptr_t fbase = (((uintptr_t)ip) + 255) & ~(uintptr_t)255;
  float* h1 = (float*)fbase;
  float* h2 = h1 + (size_t)N * NDIM;
  float* h3 = h2 + (size_t)N * NDIM;
  float* g1 = h3 + (size_t)N * NDIM;
  float* g2 = g1 + (size_t)N * NDIM;

  hipMemsetAsync(deg_d, 0, sizeof(int) * (size_t)4 * N, stream);

  int eb = (E + 255) / 256;
  int nb = (N + SCAN_ELEMS - 1) / SCAN_ELEMS;   // scan blocks (25 for N=50000)
  degree_kernel<<<eb, 256, 0, stream>>>(src, dst, deg_d, deg_s, E, N);
  scan_partial<<<dim3(nb, 2), 256, 0, stream>>>(deg_d, deg_s, bsum, N, nb);
  scan_bsum<<<1, 256, 0, stream>>>(bsum, nb);
  scan_final<<<dim3(nb, 2), 256, 0, stream>>>(deg_d, deg_s, bsum, row_d, row_s, N, nb);
  fill_kernel<<<eb, 256, 0, stream>>>(src, dst, row_d, cur_d, col_d,
                                      row_s, cur_s, col_s, E, N);

  int ab = (N + 3) / 4;
  int cb = (N + 255) / 256;
  const float* hbufs[4] = {x, h1, h2, h3};
  for (int l = 0; l < 3; ++l) {
    const float* hin = hbufs[l];
    float* hout = (float*)hbufs[l + 1];
    agg2_kernel<<<dim3(ab, 2), 256, 0, stream>>>(hin, row_d, col_d, g1,
                                                 row_s, col_s, g2, N);
    combine_kernel<<<cb, 256, 0, stream>>>(hin, g1, g2,
                                           rootw + (size_t)l * 4096,
                                           lin1 + (size_t)l * 4096,
                                           lin2 + (size_t)l * 4096,
                                           rootb + (size_t)l * 64, hout, N);
  }
  final_kernel<<<cb, 256, 0, stream>>>(x, h1, h2, h3, fw, fb, out, N);
}

// Round 3
// 525.745 us; speedup vs baseline: 1.4345x; 1.0514x over previous
//
#include <hip/hip_runtime.h>
#include <stdint.h>

#define NDIM 64
#define SCAN_ELEMS 2048   // elements per scan block (256 thr x 8)
#define FILL_EPT 8        // edges per thread in fill

// ---------------- CSR build ----------------

__global__ __launch_bounds__(256) void degree_kernel(
    const int* __restrict__ src, const int* __restrict__ dst,
    int* __restrict__ deg_d, int* __restrict__ deg_s, int E, int N) {
  int e = blockIdx.x * blockDim.x + threadIdx.x;
  if (e >= E) return;
  int s = src[e], d = dst[e];
  if ((unsigned)d < (unsigned)N) atomicAdd(&deg_d[d], 1);
  if ((unsigned)s < (unsigned)N) atomicAdd(&deg_s[s], 1);
}

// phase 1: per-block sums of deg_d (y=0) / deg_s (y=1)
__global__ __launch_bounds__(256) void scan_partial(
    const int* __restrict__ deg_d, const int* __restrict__ deg_s,
    int* __restrict__ bsum, int n, int nb) {
  const int* deg = (blockIdx.y == 0) ? deg_d : deg_s;
  int tid = threadIdx.x;
  int base = blockIdx.x * SCAN_ELEMS;
  int s = 0;
#pragma unroll
  for (int j = 0; j < 8; ++j) {
    int i = base + j * 256 + tid;
    if (i < n) s += deg[i];
  }
#pragma unroll
  for (int off = 1; off < 64; off <<= 1) s += __shfl_xor(s, off);
  __shared__ int ws[4];
  if ((tid & 63) == 0) ws[tid >> 6] = s;
  __syncthreads();
  if (tid == 0) bsum[blockIdx.y * nb + blockIdx.x] = ws[0] + ws[1] + ws[2] + ws[3];
}

// phase 2: exclusive-scan the block sums (nb <= 256), both halves
__global__ __launch_bounds__(256) void scan_bsum(int* __restrict__ bsum, int nb) {
  __shared__ int sh[256];
  int tid = threadIdx.x;
  for (int h = 0; h < 2; ++h) {
    int v = (tid < nb) ? bsum[h * nb + tid] : 0;
    sh[tid] = v;
    __syncthreads();
    for (int off = 1; off < 256; off <<= 1) {
      int t = (tid >= off) ? sh[tid - off] : 0;
      __syncthreads();
      sh[tid] += t;
      __syncthreads();
    }
    if (tid < nb) bsum[h * nb + tid] = sh[tid] - v;  // exclusive
    __syncthreads();
  }
}

// phase 3: per-block exclusive scan + block offset; writes row[0..n]
__global__ __launch_bounds__(256) void scan_final(
    const int* __restrict__ deg_d, const int* __restrict__ deg_s,
    const int* __restrict__ bsum,
    int* __restrict__ row_d, int* __restrict__ row_s, int n, int nb) {
  const int* deg = (blockIdx.y == 0) ? deg_d : deg_s;
  int* row = (blockIdx.y == 0) ? row_d : row_s;
  int tid = threadIdx.x;
  int lane = tid & 63;
  int e0 = blockIdx.x * SCAN_ELEMS + tid * 8;
  int v[8];
  int s = 0;
#pragma unroll
  for (int j = 0; j < 8; ++j) {
    int i = e0 + j;
    v[j] = (i < n) ? deg[i] : 0;
    s += v[j];
  }
  int incl = s;
#pragma unroll
  for (int off = 1; off < 64; off <<= 1) {
    int t = __shfl_up(incl, off);
    if (lane >= off) incl += t;
  }
  __shared__ int wsum[4];
  if (lane == 63) wsum[tid >> 6] = incl;
  __syncthreads();
  int woff = 0;
  int w = tid >> 6;
  for (int k = 0; k < 4; ++k)
    if (k < w) woff += wsum[k];
  int run = incl - s + woff + bsum[blockIdx.y * nb + blockIdx.x];
#pragma unroll
  for (int j = 0; j < 8; ++j) {
    int i = e0 + j;
    if (i <= n) row[i] = run;
    run += v[j];
  }
}

// XCD-local fill: group g = blockIdx & 7 only writes nodes in [lo,hi).
// All groups scan all edges (sequential reads are L2/L3-served); every
// col/cursor cache line is written by exactly one XCD -> one writeback.
__global__ __launch_bounds__(256) void fill_xcd_kernel(
    const int* __restrict__ src, const int* __restrict__ dst,
    const int* __restrict__ row_d, int* __restrict__ cur_d, int* __restrict__ col_d,
    const int* __restrict__ row_s, int* __restrict__ cur_s, int* __restrict__ col_s,
    int E, int N) {
  int g = blockIdx.x & 7;
  int chunk = blockIdx.x >> 3;
  int lo = (int)((long long)N * g >> 3);
  int hi = (int)((long long)N * (g + 1) >> 3);
  int base = chunk * (256 * FILL_EPT) + threadIdx.x;
#pragma unroll
  for (int j = 0; j < FILL_EPT; ++j) {
    int e = base + j * 256;
    if (e >= E) continue;
    int s = src[e];
    int d = dst[e];
    if (d >= lo && d < hi) {
      int p = atomicAdd(&cur_d[d], 1);
      col_d[row_d[d] + p] = s;
    }
    if (s >= lo && s < hi) {
      int q = atomicAdd(&cur_s[s], 1);
      col_s[row_s[s] + q] = d;
    }
  }
}

// ---------------- aggregation: wave per node, lane = feature; y selects direction ----------------

__global__ __launch_bounds__(256) void agg2_kernel(
    const float* __restrict__ h,
    const int* __restrict__ row_d, const int* __restrict__ col_d, float* __restrict__ g1,
    const int* __restrict__ row_s, const int* __restrict__ col_s, float* __restrict__ g2,
    int N) {
  const int* row = (blockIdx.y == 0) ? row_d : row_s;
  const int* col = (blockIdx.y == 0) ? col_d : col_s;
  float* outp = (blockIdx.y == 0) ? g1 : g2;
  int wid = blockIdx.x * 4 + (threadIdx.x >> 6);
  int lane = threadIdx.x & 63;
  if (wid >= N) return;
  int s0 = row[wid], s1 = row[wid + 1];
  float a0 = 0.f, a1 = 0.f, a2 = 0.f, a3 = 0.f;
  int p = s0;
  for (; p + 8 <= s1; p += 8) {
    int n0 = col[p], n1 = col[p + 1], n2 = col[p + 2], n3 = col[p + 3];
    int n4 = col[p + 4], n5 = col[p + 5], n6 = col[p + 6], n7 = col[p + 7];
    a0 += h[(size_t)n0 * NDIM + lane];
    a1 += h[(size_t)n1 * NDIM + lane];
    a2 += h[(size_t)n2 * NDIM + lane];
    a3 += h[(size_t)n3 * NDIM + lane];
    a0 += h[(size_t)n4 * NDIM + lane];
    a1 += h[(size_t)n5 * NDIM + lane];
    a2 += h[(size_t)n6 * NDIM + lane];
    a3 += h[(size_t)n7 * NDIM + lane];
  }
  for (; p + 4 <= s1; p += 4) {
    int n0 = col[p], n1 = col[p + 1], n2 = col[p + 2], n3 = col[p + 3];
    a0 += h[(size_t)n0 * NDIM + lane];
    a1 += h[(size_t)n1 * NDIM + lane];
    a2 += h[(size_t)n2 * NDIM + lane];
    a3 += h[(size_t)n3 * NDIM + lane];
  }
  for (; p < s1; ++p) a0 += h[(size_t)col[p] * NDIM + lane];
  float sum = (a0 + a1) + (a2 + a3);
  int cnt = s1 - s0;
  float inv = cnt > 0 ? 1.f / (float)cnt : 0.f;
  outp[(size_t)wid * NDIM + lane] = sum * inv;
}

// ---------------- combine: h_out = relu(h@R^T + b + g1@W1^T + g2@W2^T) ----------------

#define STEP3(V0, V1, V2, KROW) {                                            \
    const float4* wr4_ = (const float4*)&Wr[(KROW) * 64];                    \
    const float4* w14_ = (const float4*)&W1[(KROW) * 64];                    \
    const float4* w24_ = (const float4*)&W2[(KROW) * 64];                    \
    _Pragma("unroll")                                                        \
    for (int o4_ = 0; o4_ < 16; ++o4_) {                                     \
      float4 wa_ = wr4_[o4_], wb_ = w14_[o4_], wc_ = w24_[o4_];              \
      acc[4 * o4_ + 0] += (V0) * wa_.x + (V1) * wb_.x + (V2) * wc_.x;        \
      acc[4 * o4_ + 1] += (V0) * wa_.y + (V1) * wb_.y + (V2) * wc_.y;        \
      acc[4 * o4_ + 2] += (V0) * wa_.z + (V1) * wb_.z + (V2) * wc_.z;        \
      acc[4 * o4_ + 3] += (V0) * wa_.w + (V1) * wb_.w + (V2) * wc_.w;        \
    } }

__global__ __launch_bounds__(256) void combine_kernel(
    const float* __restrict__ h, const float* __restrict__ g1,
    const float* __restrict__ g2, const float* __restrict__ wr,
    const float* __restrict__ w1, const float* __restrict__ w2,
    const float* __restrict__ bias, float* __restrict__ hout, int N) {
  __shared__ float Wr[64 * 64];
  __shared__ float W1[64 * 64];
  __shared__ float W2[64 * 64];
  __shared__ float B[64];
  int tid = threadIdx.x;
  for (int i = 0; i < 4; ++i) {
    int f4 = i * 256 + tid;
    int o = f4 >> 4;
    int kb = (f4 & 15) << 2;
    float4 vr = ((const float4*)wr)[f4];
    float4 v1 = ((const float4*)w1)[f4];
    float4 v2 = ((const float4*)w2)[f4];
    Wr[(kb + 0) * 64 + o] = vr.x; Wr[(kb + 1) * 64 + o] = vr.y;
    Wr[(kb + 2) * 64 + o] = vr.z; Wr[(kb + 3) * 64 + o] = vr.w;
    W1[(kb + 0) * 64 + o] = v1.x; W1[(kb + 1) * 64 + o] = v1.y;
    W1[(kb + 2) * 64 + o] = v1.z; W1[(kb + 3) * 64 + o] = v1.w;
    W2[(kb + 0) * 64 + o] = v2.x; W2[(kb + 1) * 64 + o] = v2.y;
    W2[(kb + 2) * 64 + o] = v2.z; W2[(kb + 3) * 64 + o] = v2.w;
  }
  if (tid < 64) B[tid] = bias[tid];
  __syncthreads();
  int node = blockIdx.x * 256 + tid;
  if (node >= N) return;
  float acc[64];
#pragma unroll
  for (int o = 0; o < 64; ++o) acc[o] = B[o];
  const float4* hp = (const float4*)(h + (size_t)node * NDIM);
  const float4* p1 = (const float4*)(g1 + (size_t)node * NDIM);
  const float4* p2 = (const float4*)(g2 + (size_t)node * NDIM);
  float4 hc = hp[0], c1 = p1[0], c2 = p2[0];
  for (int k4 = 0; k4 < 16; ++k4) {
    float4 hn = hc, n1 = c1, n2 = c2;
    if (k4 < 15) { hn = hp[k4 + 1]; n1 = p1[k4 + 1]; n2 = p2[k4 + 1]; }
    int kb = k4 * 4;
    STEP3(hc.x, c1.x, c2.x, kb + 0);
    STEP3(hc.y, c1.y, c2.y, kb + 1);
    STEP3(hc.z, c1.z, c2.z, kb + 2);
    STEP3(hc.w, c1.w, c2.w, kb + 3);
    hc = hn; c1 = n1; c2 = n2;
  }
  float4* op = (float4*)(hout + (size_t)node * NDIM);
#pragma unroll
  for (int o4 = 0; o4 < 16; ++o4) {
    float4 v;
    v.x = fmaxf(acc[4 * o4 + 0], 0.f);
    v.y = fmaxf(acc[4 * o4 + 1], 0.f);
    v.z = fmaxf(acc[4 * o4 + 2], 0.f);
    v.w = fmaxf(acc[4 * o4 + 3], 0.f);
    op[o4] = v;
  }
}

// ---------------- final: out = [x,h1,h2,h3] @ final_w^T + final_b ----------------

#define FSTEP(V, KROW) {                                                     \
    const float4* w4_ = (const float4*)&Wt[(KROW) * 64];                     \
    _Pragma("unroll")                                                        \
    for (int o4_ = 0; o4_ < 16; ++o4_) {                                     \
      float4 w_ = w4_[o4_];                                                  \
      acc[4 * o4_ + 0] += (V) * w_.x;                                        \
      acc[4 * o4_ + 1] += (V) * w_.y;                                        \
      acc[4 * o4_ + 2] += (V) * w_.z;                                        \
      acc[4 * o4_ + 3] += (V) * w_.w;                                        \
    } }

#define FBLOCK(PTR, ABASE) {                                                 \
    const float4* ip_ = (const float4*)((PTR) + (size_t)node * NDIM);        \
    float4 c_ = ip_[0];                                                      \
    for (int k4_ = 0; k4_ < 16; ++k4_) {                                     \
      float4 n_ = c_;                                                        \
      if (k4_ < 15) n_ = ip_[k4_ + 1];                                       \
      int kr_ = (ABASE) + k4_ * 4;                                           \
      FSTEP(c_.x, kr_ + 0);                                                  \
      FSTEP(c_.y, kr_ + 1);                                                  \
      FSTEP(c_.z, kr_ + 2);                                                  \
      FSTEP(c_.w, kr_ + 3);                                                  \
      c_ = n_;                                                               \
    } }

__global__ __launch_bounds__(256) void final_kernel(
    const float* __restrict__ x, const float* __restrict__ h1,
    const float* __restrict__ h2, const float* __restrict__ h3,
    const float* __restrict__ fw, const float* __restrict__ fb,
    float* __restrict__ outp, int N) {
  __shared__ float Wt[256 * 64];
  int tid = threadIdx.x;
  for (int i = 0; i < 16; ++i) {
    int f4 = i * 256 + tid;
    int o = f4 >> 6;
    int kc = f4 & 63;
    float4 v = ((const float4*)fw)[f4];
    int kb = kc * 4;
    Wt[(kb + 0) * 64 + o] = v.x; Wt[(kb + 1) * 64 + o] = v.y;
    Wt[(kb + 2) * 64 + o] = v.z; Wt[(kb + 3) * 64 + o] = v.w;
  }
  __syncthreads();
  int node = blockIdx.x * 256 + tid;
  if (node >= N) return;
  float acc[64];
#pragma unroll
  for (int o = 0; o < 64; ++o) acc[o] = fb[o];
  FBLOCK(x, 0)
  FBLOCK(h1, 64)
  FBLOCK(h2, 128)
  FBLOCK(h3, 192)
  float4* op = (float4*)(outp + (size_t)node * NDIM);
#pragma unroll
  for (int o4 = 0; o4 < 16; ++o4) {
    float4 v;
    v.x = acc[4 * o4 + 0]; v.y = acc[4 * o4 + 1];
    v.z = acc[4 * o4 + 2]; v.w = acc[4 * o4 + 3];
    op[o4] = v;
  }
}

// ---------------- launch ----------------

extern "C" void kernel_launch(void* const* d_in, const int* in_sizes, int n_in,
                              void* d_out, int out_size, void* d_ws, size_t ws_size,
                              hipStream_t stream) {
  const float* x     = (const float*)d_in[0];
  const int*   ei    = (const int*)d_in[1];
  const float* lin1  = (const float*)d_in[2];
  const float* lin2  = (const float*)d_in[3];
  const float* rootw = (const float*)d_in[4];
  const float* rootb = (const float*)d_in[5];
  const float* fw    = (const float*)d_in[6];
  const float* fb    = (const float*)d_in[7];
  float* out = (float*)d_out;

  int N = in_sizes[0] / NDIM;
  int E = in_sizes[1] / 2;
  const int* src = ei;
  const int* dst = ei + E;

  int* ip = (int*)d_ws;
  int* deg_d = ip; ip += N;
  int* deg_s = ip; ip += N;
  int* cur_d = ip; ip += N;
  int* cur_s = ip; ip += N;
  int* row_d = ip; ip += N + 1;
  int* row_s = ip; ip += N + 1;
  int* bsum  = ip; ip += 256;
  int* col_d = ip; ip += E;
  int* col_s = ip; ip += E;
  uintptr_t fbase = (((uintptr_t)ip) + 255) & ~(uintptr_t)255;
  float* h1 = (float*)fbase;
  float* h2 = h1 + (size_t)N * NDIM;
  float* h3 = h2 + (size_t)N * NDIM;
  float* g1 = h3 + (size_t)N * NDIM;
  float* g2 = g1 + (size_t)N * NDIM;

  hipMemsetAsync(deg_d, 0, sizeof(int) * (size_t)4 * N, stream);

  int eb = (E + 255) / 256;
  int nb = (N + SCAN_ELEMS - 1) / SCAN_ELEMS;
  degree_kernel<<<eb, 256, 0, stream>>>(src, dst, deg_d, deg_s, E, N);
  scan_partial<<<dim3(nb, 2), 256, 0, stream>>>(deg_d, deg_s, bsum, N, nb);
  scan_bsum<<<1, 256, 0, stream>>>(bsum, nb);
  scan_final<<<dim3(nb, 2), 256, 0, stream>>>(deg_d, deg_s, bsum, row_d, row_s, N, nb);
  int nchunk = (E + 256 * FILL_EPT - 1) / (256 * FILL_EPT);
  fill_xcd_kernel<<<nchunk * 8, 256, 0, stream>>>(src, dst, row_d, cur_d, col_d,
                                                  row_s, cur_s, col_s, E, N);

  int ab = (N + 3) / 4;
  int cb = (N + 255) / 256;
  const float* hbufs[4] = {x, h1, h2, h3};
  for (int l = 0; l < 3; ++l) {
    const float* hin = hbufs[l];
    float* hout = (float*)hbufs[l + 1];
    agg2_kernel<<<dim3(ab, 2), 256, 0, stream>>>(hin, row_d, col_d, g1,
                                                 row_s, col_s, g2, N);
    combine_kernel<<<cb, 256, 0, stream>>>(hin, g1, g2,
                                           rootw + (size_t)l * 4096,
                                           lin1 + (size_t)l * 4096,
                                           lin2 + (size_t)l * 4096,
                                           rootb + (size_t)l * 64, hout, N);
  }
  final_kernel<<<cb, 256, 0, stream>>>(x, h1, h2, h3, fw, fb, out, N);
}

// Round 4
// 470.184 us; speedup vs baseline: 1.6040x; 1.1182x over previous
//
#include <hip/hip_runtime.h>
#include <stdint.h>

#define NDIM 64
#define SCAN_ELEMS 2048   // elements per scan block (256 thr x 8)
#define NCHK 16           // edge chunks
#define NGRP 16           // node-range groups
#define RMAX 3200         // max nodes per group (ceil(50000/16)=3125)

// ---------------- CSR build: atomic-free chunked counting sort ----------------
// Phase 1: block (c,g) counts keys of chunk c falling in node-range g into LDS.
__global__ __launch_bounds__(256) void hist_kernel(
    const int* __restrict__ src, const int* __restrict__ dst,
    int* __restrict__ Hd, int* __restrict__ Hs, int E, int N, int chunk) {
  int c = blockIdx.x, g = blockIdx.y;
  int lo = (int)((long long)N * g / NGRP);
  int hi = (int)((long long)N * (g + 1) / NGRP);
  int range = hi - lo;
  __shared__ int cntd[RMAX];
  __shared__ int cnts[RMAX];
  for (int i = threadIdx.x; i < range; i += 256) { cntd[i] = 0; cnts[i] = 0; }
  __syncthreads();
  int e0 = c * chunk, e1 = min(E, e0 + chunk);
  for (int e = e0 + (int)threadIdx.x * 4; e < e1; e += 1024) {
    if (e + 4 <= e1) {
      int4 s4 = *(const int4*)(src + e);
      int4 d4 = *(const int4*)(dst + e);
      if (d4.x >= lo && d4.x < hi) atomicAdd(&cntd[d4.x - lo], 1);
      if (d4.y >= lo && d4.y < hi) atomicAdd(&cntd[d4.y - lo], 1);
      if (d4.z >= lo && d4.z < hi) atomicAdd(&cntd[d4.z - lo], 1);
      if (d4.w >= lo && d4.w < hi) atomicAdd(&cntd[d4.w - lo], 1);
      if (s4.x >= lo && s4.x < hi) atomicAdd(&cnts[s4.x - lo], 1);
      if (s4.y >= lo && s4.y < hi) atomicAdd(&cnts[s4.y - lo], 1);
      if (s4.z >= lo && s4.z < hi) atomicAdd(&cnts[s4.z - lo], 1);
      if (s4.w >= lo && s4.w < hi) atomicAdd(&cnts[s4.w - lo], 1);
    } else {
      for (int k = e; k < e1; ++k) {
        int s = src[k], d = dst[k];
        if (d >= lo && d < hi) atomicAdd(&cntd[d - lo], 1);
        if (s >= lo && s < hi) atomicAdd(&cnts[s - lo], 1);
      }
    }
  }
  __syncthreads();
  for (int i = threadIdx.x; i < range; i += 256) {
    Hd[(size_t)c * N + lo + i] = cntd[i];
    Hs[(size_t)c * N + lo + i] = cnts[i];
  }
}

// degree = sum of per-chunk counts
__global__ __launch_bounds__(256) void degsum_kernel(
    const int* __restrict__ Hd, const int* __restrict__ Hs,
    int* __restrict__ deg_d, int* __restrict__ deg_s, int N) {
  int n = blockIdx.x * 256 + threadIdx.x;
  if (n >= N) return;
  int sd = 0, ss = 0;
#pragma unroll
  for (int c = 0; c < NCHK; ++c) {
    sd += Hd[(size_t)c * N + n];
    ss += Hs[(size_t)c * N + n];
  }
  deg_d[n] = sd;
  deg_s[n] = ss;
}

// phase 1 of row scan: per-block sums of deg_d (y=0) / deg_s (y=1)
__global__ __launch_bounds__(256) void scan_partial(
    const int* __restrict__ deg_d, const int* __restrict__ deg_s,
    int* __restrict__ bsum, int n, int nb) {
  const int* deg = (blockIdx.y == 0) ? deg_d : deg_s;
  int tid = threadIdx.x;
  int base = blockIdx.x * SCAN_ELEMS;
  int s = 0;
#pragma unroll
  for (int j = 0; j < 8; ++j) {
    int i = base + j * 256 + tid;
    if (i < n) s += deg[i];
  }
#pragma unroll
  for (int off = 1; off < 64; off <<= 1) s += __shfl_xor(s, off);
  __shared__ int ws[4];
  if ((tid & 63) == 0) ws[tid >> 6] = s;
  __syncthreads();
  if (tid == 0) bsum[blockIdx.y * nb + blockIdx.x] = ws[0] + ws[1] + ws[2] + ws[3];
}

__global__ __launch_bounds__(256) void scan_bsum(int* __restrict__ bsum, int nb) {
  __shared__ int sh[256];
  int tid = threadIdx.x;
  for (int h = 0; h < 2; ++h) {
    int v = (tid < nb) ? bsum[h * nb + tid] : 0;
    sh[tid] = v;
    __syncthreads();
    for (int off = 1; off < 256; off <<= 1) {
      int t = (tid >= off) ? sh[tid - off] : 0;
      __syncthreads();
      sh[tid] += t;
      __syncthreads();
    }
    if (tid < nb) bsum[h * nb + tid] = sh[tid] - v;  // exclusive
    __syncthreads();
  }
}

__global__ __launch_bounds__(256) void scan_final(
    const int* __restrict__ deg_d, const int* __restrict__ deg_s,
    const int* __restrict__ bsum,
    int* __restrict__ row_d, int* __restrict__ row_s, int n, int nb) {
  const int* deg = (blockIdx.y == 0) ? deg_d : deg_s;
  int* row = (blockIdx.y == 0) ? row_d : row_s;
  int tid = threadIdx.x;
  int lane = tid & 63;
  int e0 = blockIdx.x * SCAN_ELEMS + tid * 8;
  int v[8];
  int s = 0;
#pragma unroll
  for (int j = 0; j < 8; ++j) {
    int i = e0 + j;
    v[j] = (i < n) ? deg[i] : 0;
    s += v[j];
  }
  int incl = s;
#pragma unroll
  for (int off = 1; off < 64; off <<= 1) {
    int t = __shfl_up(incl, off);
    if (lane >= off) incl += t;
  }
  __shared__ int wsum[4];
  if (lane == 63) wsum[tid >> 6] = incl;
  __syncthreads();
  int woff = 0;
  int w = tid >> 6;
  for (int k = 0; k < 4; ++k)
    if (k < w) woff += wsum[k];
  int run = incl - s + woff + bsum[blockIdx.y * nb + blockIdx.x];
#pragma unroll
  for (int j = 0; j < 8; ++j) {
    int i = e0 + j;
    if (i <= n) row[i] = run;
    run += v[j];
  }
}

// phase 2: convert H[c][n] counts into absolute start cursors row[n]+prefix_c
__global__ __launch_bounds__(256) void cursor_kernel(
    int* __restrict__ Hd, int* __restrict__ Hs,
    const int* __restrict__ row_d, const int* __restrict__ row_s, int N) {
  int n = blockIdx.x * 256 + threadIdx.x;
  if (n >= N) return;
  int rd = row_d[n], rs = row_s[n];
#pragma unroll
  for (int c = 0; c < NCHK; ++c) {
    int t = Hd[(size_t)c * N + n]; Hd[(size_t)c * N + n] = rd; rd += t;
    t = Hs[(size_t)c * N + n];     Hs[(size_t)c * N + n] = rs; rs += t;
  }
}

// phase 3: scatter with LDS cursors (no global atomics)
__global__ __launch_bounds__(256) void scatter_kernel(
    const int* __restrict__ src, const int* __restrict__ dst,
    const int* __restrict__ Hd, const int* __restrict__ Hs,
    int* __restrict__ col_d, int* __restrict__ col_s, int E, int N, int chunk) {
  int c = blockIdx.x, g = blockIdx.y;
  int lo = (int)((long long)N * g / NGRP);
  int hi = (int)((long long)N * (g + 1) / NGRP);
  int range = hi - lo;
  __shared__ int curd[RMAX];
  __shared__ int curs[RMAX];
  for (int i = threadIdx.x; i < range; i += 256) {
    curd[i] = Hd[(size_t)c * N + lo + i];
    curs[i] = Hs[(size_t)c * N + lo + i];
  }
  __syncthreads();
  int e0 = c * chunk, e1 = min(E, e0 + chunk);
  for (int e = e0 + (int)threadIdx.x * 4; e < e1; e += 1024) {
    if (e + 4 <= e1) {
      int4 s4 = *(const int4*)(src + e);
      int4 d4 = *(const int4*)(dst + e);
      if (d4.x >= lo && d4.x < hi) { int p = atomicAdd(&curd[d4.x - lo], 1); col_d[p] = s4.x; }
      if (d4.y >= lo && d4.y < hi) { int p = atomicAdd(&curd[d4.y - lo], 1); col_d[p] = s4.y; }
      if (d4.z >= lo && d4.z < hi) { int p = atomicAdd(&curd[d4.z - lo], 1); col_d[p] = s4.z; }
      if (d4.w >= lo && d4.w < hi) { int p = atomicAdd(&curd[d4.w - lo], 1); col_d[p] = s4.w; }
      if (s4.x >= lo && s4.x < hi) { int p = atomicAdd(&curs[s4.x - lo], 1); col_s[p] = d4.x; }
      if (s4.y >= lo && s4.y < hi) { int p = atomicAdd(&curs[s4.y - lo], 1); col_s[p] = d4.y; }
      if (s4.z >= lo && s4.z < hi) { int p = atomicAdd(&curs[s4.z - lo], 1); col_s[p] = d4.z; }
      if (s4.w >= lo && s4.w < hi) { int p = atomicAdd(&curs[s4.w - lo], 1); col_s[p] = d4.w; }
    } else {
      for (int k = e; k < e1; ++k) {
        int s = src[k], d = dst[k];
        if (d >= lo && d < hi) { int p = atomicAdd(&curd[d - lo], 1); col_d[p] = s; }
        if (s >= lo && s < hi) { int p = atomicAdd(&curs[s - lo], 1); col_s[p] = d; }
      }
    }
  }
}

// ---------------- aggregation: wave per node, lane = feature; y selects direction ----------------

__global__ __launch_bounds__(256) void agg2_kernel(
    const float* __restrict__ h,
    const int* __restrict__ row_d, const int* __restrict__ col_d, float* __restrict__ g1,
    const int* __restrict__ row_s, const int* __restrict__ col_s, float* __restrict__ g2,
    int N) {
  const int* row = (blockIdx.y == 0) ? row_d : row_s;
  const int* col = (blockIdx.y == 0) ? col_d : col_s;
  float* outp = (blockIdx.y == 0) ? g1 : g2;
  int wid = blockIdx.x * 4 + (threadIdx.x >> 6);
  int lane = threadIdx.x & 63;
  if (wid >= N) return;
  int s0 = row[wid], s1 = row[wid + 1];
  float a0 = 0.f, a1 = 0.f, a2 = 0.f, a3 = 0.f;
  int p = s0;
  for (; p + 8 <= s1; p += 8) {
    int n0 = col[p], n1 = col[p + 1], n2 = col[p + 2], n3 = col[p + 3];
    int n4 = col[p + 4], n5 = col[p + 5], n6 = col[p + 6], n7 = col[p + 7];
    a0 += h[(size_t)n0 * NDIM + lane];
    a1 += h[(size_t)n1 * NDIM + lane];
    a2 += h[(size_t)n2 * NDIM + lane];
    a3 += h[(size_t)n3 * NDIM + lane];
    a0 += h[(size_t)n4 * NDIM + lane];
    a1 += h[(size_t)n5 * NDIM + lane];
    a2 += h[(size_t)n6 * NDIM + lane];
    a3 += h[(size_t)n7 * NDIM + lane];
  }
  for (; p + 4 <= s1; p += 4) {
    int n0 = col[p], n1 = col[p + 1], n2 = col[p + 2], n3 = col[p + 3];
    a0 += h[(size_t)n0 * NDIM + lane];
    a1 += h[(size_t)n1 * NDIM + lane];
    a2 += h[(size_t)n2 * NDIM + lane];
    a3 += h[(size_t)n3 * NDIM + lane];
  }
  for (; p < s1; ++p) a0 += h[(size_t)col[p] * NDIM + lane];
  float sum = (a0 + a1) + (a2 + a3);
  int cnt = s1 - s0;
  float inv = cnt > 0 ? 1.f / (float)cnt : 0.f;
  outp[(size_t)wid * NDIM + lane] = sum * inv;
}

// ---------------- combine: h_out = relu(h@R^T + b + g1@W1^T + g2@W2^T) ----------------

#define STEP3(V0, V1, V2, KROW) {                                            \
    const float4* wr4_ = (const float4*)&Wr[(KROW) * 64];                    \
    const float4* w14_ = (const float4*)&W1[(KROW) * 64];                    \
    const float4* w24_ = (const float4*)&W2[(KROW) * 64];                    \
    _Pragma("unroll")                                                        \
    for (int o4_ = 0; o4_ < 16; ++o4_) {                                     \
      float4 wa_ = wr4_[o4_], wb_ = w14_[o4_], wc_ = w24_[o4_];              \
      acc[4 * o4_ + 0] += (V0) * wa_.x + (V1) * wb_.x + (V2) * wc_.x;        \
      acc[4 * o4_ + 1] += (V0) * wa_.y + (V1) * wb_.y + (V2) * wc_.y;        \
      acc[4 * o4_ + 2] += (V0) * wa_.z + (V1) * wb_.z + (V2) * wc_.z;        \
      acc[4 * o4_ + 3] += (V0) * wa_.w + (V1) * wb_.w + (V2) * wc_.w;        \
    } }

__global__ __launch_bounds__(256) void combine_kernel(
    const float* __restrict__ h, const float* __restrict__ g1,
    const float* __restrict__ g2, const float* __restrict__ wr,
    const float* __restrict__ w1, const float* __restrict__ w2,
    const float* __restrict__ bias, float* __restrict__ hout, int N) {
  __shared__ float Wr[64 * 64];
  __shared__ float W1[64 * 64];
  __shared__ float W2[64 * 64];
  __shared__ float B[64];
  int tid = threadIdx.x;
  for (int i = 0; i < 4; ++i) {
    int f4 = i * 256 + tid;
    int o = f4 >> 4;
    int kb = (f4 & 15) << 2;
    float4 vr = ((const float4*)wr)[f4];
    float4 v1 = ((const float4*)w1)[f4];
    float4 v2 = ((const float4*)w2)[f4];
    Wr[(kb + 0) * 64 + o] = vr.x; Wr[(kb + 1) * 64 + o] = vr.y;
    Wr[(kb + 2) * 64 + o] = vr.z; Wr[(kb + 3) * 64 + o] = vr.w;
    W1[(kb + 0) * 64 + o] = v1.x; W1[(kb + 1) * 64 + o] = v1.y;
    W1[(kb + 2) * 64 + o] = v1.z; W1[(kb + 3) * 64 + o] = v1.w;
    W2[(kb + 0) * 64 + o] = v2.x; W2[(kb + 1) * 64 + o] = v2.y;
    W2[(kb + 2) * 64 + o] = v2.z; W2[(kb + 3) * 64 + o] = v2.w;
  }
  if (tid < 64) B[tid] = bias[tid];
  __syncthreads();
  int node = blockIdx.x * 256 + tid;
  if (node >= N) return;
  float acc[64];
#pragma unroll
  for (int o = 0; o < 64; ++o) acc[o] = B[o];
  const float4* hp = (const float4*)(h + (size_t)node * NDIM);
  const float4* p1 = (const float4*)(g1 + (size_t)node * NDIM);
  const float4* p2 = (const float4*)(g2 + (size_t)node * NDIM);
  float4 hc = hp[0], c1 = p1[0], c2 = p2[0];
  for (int k4 = 0; k4 < 16; ++k4) {
    float4 hn = hc, n1 = c1, n2 = c2;
    if (k4 < 15) { hn = hp[k4 + 1]; n1 = p1[k4 + 1]; n2 = p2[k4 + 1]; }
    int kb = k4 * 4;
    STEP3(hc.x, c1.x, c2.x, kb + 0);
    STEP3(hc.y, c1.y, c2.y, kb + 1);
    STEP3(hc.z, c1.z, c2.z, kb + 2);
    STEP3(hc.w, c1.w, c2.w, kb + 3);
    hc = hn; c1 = n1; c2 = n2;
  }
  float4* op = (float4*)(hout + (size_t)node * NDIM);
#pragma unroll
  for (int o4 = 0; o4 < 16; ++o4) {
    float4 v;
    v.x = fmaxf(acc[4 * o4 + 0], 0.f);
    v.y = fmaxf(acc[4 * o4 + 1], 0.f);
    v.z = fmaxf(acc[4 * o4 + 2], 0.f);
    v.w = fmaxf(acc[4 * o4 + 3], 0.f);
    op[o4] = v;
  }
}

// ---------------- final: out = [x,h1,h2,h3] @ final_w^T + final_b ----------------

#define FSTEP(V, KROW) {                                                     \
    const float4* w4_ = (const float4*)&Wt[(KROW) * 64];                     \
    _Pragma("unroll")                                                        \
    for (int o4_ = 0; o4_ < 16; ++o4_) {                                     \
      float4 w_ = w4_[o4_];                                                  \
      acc[4 * o4_ + 0] += (V) * w_.x;                                        \
      acc[4 * o4_ + 1] += (V) * w_.y;                                        \
      acc[4 * o4_ + 2] += (V) * w_.z;                                        \
      acc[4 * o4_ + 3] += (V) * w_.w;                                        \
    } }

#define FBLOCK(PTR, ABASE) {                                                 \
    const float4* ip_ = (const float4*)((PTR) + (size_t)node * NDIM);        \
    float4 c_ = ip_[0];                                                      \
    for (int k4_ = 0; k4_ < 16; ++k4_) {                                     \
      float4 n_ = c_;                                                        \
      if (k4_ < 15) n_ = ip_[k4_ + 1];                                       \
      int kr_ = (ABASE) + k4_ * 4;                                           \
      FSTEP(c_.x, kr_ + 0);                                                  \
      FSTEP(c_.y, kr_ + 1);                                                  \
      FSTEP(c_.z, kr_ + 2);                                                  \
      FSTEP(c_.w, kr_ + 3);                                                  \
      c_ = n_;                                                               \
    } }

__global__ __launch_bounds__(256) void final_kernel(
    const float* __restrict__ x, const float* __restrict__ h1,
    const float* __restrict__ h2, const float* __restrict__ h3,
    const float* __restrict__ fw, const float* __restrict__ fb,
    float* __restrict__ outp, int N) {
  __shared__ float Wt[256 * 64];
  int tid = threadIdx.x;
  for (int i = 0; i < 16; ++i) {
    int f4 = i * 256 + tid;
    int o = f4 >> 6;
    int kc = f4 & 63;
    float4 v = ((const float4*)fw)[f4];
    int kb = kc * 4;
    Wt[(kb + 0) * 64 + o] = v.x; Wt[(kb + 1) * 64 + o] = v.y;
    Wt[(kb + 2) * 64 + o] = v.z; Wt[(kb + 3) * 64 + o] = v.w;
  }
  __syncthreads();
  int node = blockIdx.x * 256 + tid;
  if (node >= N) return;
  float acc[64];
#pragma unroll
  for (int o = 0; o < 64; ++o) acc[o] = fb[o];
  FBLOCK(x, 0)
  FBLOCK(h1, 64)
  FBLOCK(h2, 128)
  FBLOCK(h3, 192)
  float4* op = (float4*)(outp + (size_t)node * NDIM);
#pragma unroll
  for (int o4 = 0; o4 < 16; ++o4) {
    float4 v;
    v.x = acc[4 * o4 + 0]; v.y = acc[4 * o4 + 1];
    v.z = acc[4 * o4 + 2]; v.w = acc[4 * o4 + 3];
    op[o4] = v;
  }
}

// ---------------- launch ----------------

extern "C" void kernel_launch(void* const* d_in, const int* in_sizes, int n_in,
                              void* d_out, int out_size, void* d_ws, size_t ws_size,
                              hipStream_t stream) {
  const float* x     = (const float*)d_in[0];
  const int*   ei    = (const int*)d_in[1];
  const float* lin1  = (const float*)d_in[2];
  const float* lin2  = (const float*)d_in[3];
  const float* rootw = (const float*)d_in[4];
  const float* rootb = (const float*)d_in[5];
  const float* fw    = (const float*)d_in[6];
  const float* fb    = (const float*)d_in[7];
  float* out = (float*)d_out;

  int N = in_sizes[0] / NDIM;
  int E = in_sizes[1] / 2;
  const int* src = ei;
  const int* dst = ei + E;

  int* ip = (int*)d_ws;
  int* Hd    = ip; ip += (size_t)NCHK * N;
  int* Hs    = ip; ip += (size_t)NCHK * N;
  int* deg_d = ip; ip += N;
  int* deg_s = ip; ip += N;
  int* row_d = ip; ip += N + 1;
  int* row_s = ip; ip += N + 1;
  int* bsum  = ip; ip += 256;
  int* col_d = ip; ip += E;
  int* col_s = ip; ip += E;
  uintptr_t fbase = (((uintptr_t)ip) + 255) & ~(uintptr_t)255;
  float* h1 = (float*)fbase;
  float* h2 = h1 + (size_t)N * NDIM;
  float* h3 = h2 + (size_t)N * NDIM;
  float* g1 = h3 + (size_t)N * NDIM;
  float* g2 = g1 + (size_t)N * NDIM;

  int chunk = (E + NCHK - 1) / NCHK;
  int nb = (N + SCAN_ELEMS - 1) / SCAN_ELEMS;
  int nblk = (N + 255) / 256;

  hist_kernel<<<dim3(NCHK, NGRP), 256, 0, stream>>>(src, dst, Hd, Hs, E, N, chunk);
  degsum_kernel<<<nblk, 256, 0, stream>>>(Hd, Hs, deg_d, deg_s, N);
  scan_partial<<<dim3(nb, 2), 256, 0, stream>>>(deg_d, deg_s, bsum, N, nb);
  scan_bsum<<<1, 256, 0, stream>>>(bsum, nb);
  scan_final<<<dim3(nb, 2), 256, 0, stream>>>(deg_d, deg_s, bsum, row_d, row_s, N, nb);
  cursor_kernel<<<nblk, 256, 0, stream>>>(Hd, Hs, row_d, row_s, N);
  scatter_kernel<<<dim3(NCHK, NGRP), 256, 0, stream>>>(src, dst, Hd, Hs,
                                                       col_d, col_s, E, N, chunk);

  int ab = (N + 3) / 4;
  const float* hbufs[4] = {x, h1, h2, h3};
  for (int l = 0; l < 3; ++l) {
    const float* hin = hbufs[l];
    float* hout = (float*)hbufs[l + 1];
    agg2_kernel<<<dim3(ab, 2), 256, 0, stream>>>(hin, row_d, col_d, g1,
                                                 row_s, col_s, g2, N);
    combine_kernel<<<nblk, 256, 0, stream>>>(hin, g1, g2,
                                             rootw + (size_t)l * 4096,
                                             lin1 + (size_t)l * 4096,
                                             lin2 + (size_t)l * 4096,
                                             rootb + (size_t)l * 64, hout, N);
  }
  final_kernel<<<nblk, 256, 0, stream>>>(x, h1, h2, h3, fw, fb, out, N);
}